// Round 1
// baseline (385.449 us; speedup 1.0000x reference)
//
#include <hip/hip_runtime.h>

#define NCLS 64
#define TDIM 512

__global__ __launch_bounds__(64) void crf_nll_kernel(
    const float* __restrict__ logits,   // [N, T, C] f32
    const int*   __restrict__ lengths,  // [N] i32
    const int*   __restrict__ tags,     // [N, T] i32
    const float* __restrict__ trans,    // [C, C] f32
    float* __restrict__ out, int N)
{
    const int n    = blockIdx.x;
    if (n >= N) return;
    const int lane = threadIdx.x;   // class index i, 0..63

    __shared__ __align__(16) float e_lds[NCLS];

    // ---- load transition row `lane` into registers ----
    float trow[NCLS];
    #pragma unroll
    for (int j = 0; j < NCLS; j += 4) {
        const float4 v = *reinterpret_cast<const float4*>(&trans[lane * NCLS + j]);
        trow[j]   = v.x; trow[j+1] = v.y; trow[j+2] = v.z; trow[j+3] = v.w;
    }
    float tmax = -3.0e38f, tsum = 0.f;
    #pragma unroll
    for (int j = 0; j < NCLS; ++j) { tmax = fmaxf(tmax, trow[j]); tsum += trow[j]; }
    // wave max over all T entries -> mT (uniform across lanes)
    float mT = tmax;
    #pragma unroll
    for (int o = 32; o; o >>= 1) mT = fmaxf(mT, __shfl_xor(mT, o));
    // exp-space transition row: expT[i][j] = exp(T[i][j] - mT)  (<= 1)
    #pragma unroll
    for (int j = 0; j < NCLS; ++j) trow[j] = __expf(trow[j] - mT);

    const int len = lengths[n];               // in [1, T-1]
    const float* lg = logits + (size_t)n * TDIM * NCLS;
    const float INV_C = 1.0f / (float)NCLS;

    // ---- alpha recurrence ----
    float alpha = 0.f;
    float lg_cur = lg[lane];                  // logits[n, 0, lane]

    for (int t = 0; t < len; ++t) {
        // prefetch next step's logit early (hide HBM/L2 latency under compute)
        float lg_next = 0.f;
        if (t + 1 < len) lg_next = lg[(size_t)(t + 1) * NCLS + lane];

        // wave max of alpha
        float mA = alpha;
        #pragma unroll
        for (int o = 32; o; o >>= 1) mA = fmaxf(mA, __shfl_xor(mA, o));

        // e[j] = exp(alpha[j] - mA), broadcast via LDS
        e_lds[lane] = __expf(alpha - mA);
        // same-wave LDS ops are processed in order; fence so the reads below
        // see the write without draining vmcnt (keeps the logit prefetch alive)
        asm volatile("s_waitcnt lgkmcnt(0)" ::: "memory");

        // dot[i] = sum_j expT[i,j] * e[j]   (broadcast float4 LDS reads)
        float d0 = 0.f, d1 = 0.f, d2 = 0.f, d3 = 0.f;
        #pragma unroll
        for (int j = 0; j < NCLS; j += 4) {
            const float4 ev = *reinterpret_cast<const float4*>(&e_lds[j]);
            d0 = fmaf(trow[j],   ev.x, d0);
            d1 = fmaf(trow[j+1], ev.y, d1);
            d2 = fmaf(trow[j+2], ev.z, d2);
            d3 = fmaf(trow[j+3], ev.w, d3);
        }
        const float dot = (d0 + d1) + (d2 + d3);

        // alpha' = logit/C + mA + mT + ln(dot)
        alpha = fmaf(lg_cur, INV_C, mA + mT + __logf(dot));
        lg_cur = lg_next;
    }

    // partition = sum_i alpha[i] at t = len-1
    float part = alpha;
    #pragma unroll
    for (int o = 32; o; o >>= 1) part += __shfl_xor(part, o);

    // ---- gold score ----
    // gold = logits[0,tags[0]] + sum_j T[tags[0],j]
    //      + sum_{m=1..len} ( T[tags[m],tags[m-1]] + logits[m,tags[m]] )
    const int* tg = tags + (size_t)n * TDIM;
    float g = 0.f;
    for (int m = 1 + lane; m <= len; m += 64) {
        const int tm = tg[m];
        const int tp = tg[m - 1];
        g += trans[tm * NCLS + tp] + lg[(size_t)m * NCLS + tm];
    }
    #pragma unroll
    for (int o = 32; o; o >>= 1) g += __shfl_xor(g, o);

    const int   t0 = tg[0];
    const float rs = __shfl(tsum, t0);   // row-sum of T at row tags[0]

    if (lane == 0) {
        const float first = lg[t0] + rs;
        out[n] = part - (g + first);
    }
}

extern "C" void kernel_launch(void* const* d_in, const int* in_sizes, int n_in,
                              void* d_out, int out_size, void* d_ws, size_t ws_size,
                              hipStream_t stream) {
    const float* logits  = (const float*)d_in[0];
    const int*   lengths = (const int*)  d_in[1];
    const int*   tags    = (const int*)  d_in[2];
    const float* trans   = (const float*)d_in[3];
    float* out = (float*)d_out;
    const int N = in_sizes[1];   // 512

    crf_nll_kernel<<<N, 64, 0, stream>>>(logits, lengths, tags, trans, out, N);
}

// Round 2
// 215.974 us; speedup vs baseline: 1.7847x; 1.7847x over previous
//
#include <hip/hip_runtime.h>

#define NCLS 64
#define TDIM 512

__global__ __launch_bounds__(64) void crf_nll_kernel(
    const float* __restrict__ logits,   // [N, T, C] f32
    const int*   __restrict__ lengths,  // [N] i32
    const int*   __restrict__ tags,     // [N, T] i32
    const float* __restrict__ trans,    // [C, C] f32
    float* __restrict__ out, int N)
{
    const int n    = blockIdx.x;
    if (n >= N) return;
    const int lane = threadIdx.x;   // class index i, 0..63

    __shared__ __align__(16) float f_lds[NCLS];

    // ---- load transition row `lane`, compute mT, row-sum, exp-space rows ----
    float trow[NCLS];
    #pragma unroll
    for (int j = 0; j < NCLS; j += 4) {
        const float4 v = *reinterpret_cast<const float4*>(&trans[lane * NCLS + j]);
        trow[j]   = v.x; trow[j+1] = v.y; trow[j+2] = v.z; trow[j+3] = v.w;
    }
    float tmax = -3.0e38f, tsum = 0.f;
    #pragma unroll
    for (int j = 0; j < NCLS; ++j) { tmax = fmaxf(tmax, trow[j]); tsum += trow[j]; }
    float mT = tmax;
    #pragma unroll
    for (int o = 32; o; o >>= 1) mT = fmaxf(mT, __shfl_xor(mT, o));
    // expT[i][j] = exp(T[i][j] - mT) / 64  (fold the 1/64 LSE normalizer in)
    #pragma unroll
    for (int j = 0; j < NCLS; ++j) trow[j] = __expf(trow[j] - mT) * 0.015625f;

    const int len = lengths[n];               // in [1, T-1]
    const float* lg = logits + (size_t)n * TDIM * NCLS;
    const float INV_C = 1.0f / (float)NCLS;

    // ---- alpha recurrence in pure exp-space ----
    // alpha_i(t) = B_t + ln f_i,  B_t = t*(mT + ln64) + B_renorm  (uniform, analytic)
    // f'_i = (sum_j expT[i,j] * f_j) * p_i,  p_i = exp(logit_t,i / 64)
    float f = 1.0f;     // alpha = 0  ->  f = 1, B = 0
    float B = 0.0f;     // accumulated renorm logs only

    float p_cur   = __expf(lg[lane] * INV_C);      // p for t=0
    float lg_next = lg[NCLS + lane];               // logits row 1 (always exists)

    for (int t = 0; t < len; ++t) {
        // prefetch logits row t+2 (2-deep pipeline, off critical path)
        int idx = t + 2; if (idx > TDIM - 1) idx = TDIM - 1;
        const float lg_t2 = lg[(size_t)idx * NCLS + lane];
        const float p_next = __expf(lg_next * INV_C);

        // broadcast f across the wave via LDS (same-wave, lgkm fence only:
        // keeps the global prefetch (vmcnt) in flight across the step)
        f_lds[lane] = f;
        asm volatile("s_waitcnt lgkmcnt(0)" ::: "memory");

        float d0 = 0.f, d1 = 0.f, d2 = 0.f, d3 = 0.f;
        float d4 = 0.f, d5 = 0.f, d6 = 0.f, d7 = 0.f;
        #pragma unroll
        for (int j = 0; j < NCLS; j += 8) {
            const float4 a = *reinterpret_cast<const float4*>(&f_lds[j]);
            const float4 b = *reinterpret_cast<const float4*>(&f_lds[j + 4]);
            d0 = fmaf(trow[j + 0], a.x, d0);
            d1 = fmaf(trow[j + 1], a.y, d1);
            d2 = fmaf(trow[j + 2], a.z, d2);
            d3 = fmaf(trow[j + 3], a.w, d3);
            d4 = fmaf(trow[j + 4], b.x, d4);
            d5 = fmaf(trow[j + 5], b.y, d5);
            d6 = fmaf(trow[j + 6], b.z, d6);
            d7 = fmaf(trow[j + 7], b.w, d7);
        }
        const float dot = ((d0 + d1) + (d2 + d3)) + ((d4 + d5) + (d6 + d7));

        f = dot * p_cur;
        p_cur = p_next;
        lg_next = lg_t2;

        // periodic renorm: keeps f in fp32 range for arbitrary inputs
        if ((t & 63) == 63) {
            float r = __shfl(f, 0);
            r = fmaxf(r, 1e-30f);
            f *= __builtin_amdgcn_rcpf(r);
            B += __logf(r);
        }
    }

    // ---- gold score (off critical path, after the serial chain) ----
    const int* tg = tags + (size_t)n * TDIM;
    float g = 0.f;
    for (int m = 1 + lane; m <= len; m += 64) {
        const int tm = tg[m];
        const int tp = tg[m - 1];
        g += trans[tm * NCLS + tp] + lg[(size_t)m * NCLS + tm];
    }

    // ---- combine: out = 64*B_len + sum_i(ln f_i - g_i) - first ----
    const float a = __logf(f);
    float v = a - g;
    #pragma unroll
    for (int o = 32; o; o >>= 1) v += __shfl_xor(v, o);

    const int   t0 = tg[0];
    const float rs = __shfl(tsum, t0);   // row-sum of T at row tags[0]

    if (lane == 0) {
        const float Bt    = (float)len * (mT + 4.1588830833596715f) + B; // ln(64)
        const float first = lg[t0] + rs;
        out[n] = 64.0f * Bt + v - first;
    }
}

extern "C" void kernel_launch(void* const* d_in, const int* in_sizes, int n_in,
                              void* d_out, int out_size, void* d_ws, size_t ws_size,
                              hipStream_t stream) {
    const float* logits  = (const float*)d_in[0];
    const int*   lengths = (const int*)  d_in[1];
    const int*   tags    = (const int*)  d_in[2];
    const float* trans   = (const float*)d_in[3];
    float* out = (float*)d_out;
    const int N = in_sizes[1];   // 512

    crf_nll_kernel<<<N, 64, 0, stream>>>(logits, lengths, tags, trans, out, N);
}

// Round 3
// 175.600 us; speedup vs baseline: 2.1950x; 1.2299x over previous
//
#include <hip/hip_runtime.h>

#define NCLS 64
#define TDIM 512
#define PD   8   // prefetch depth (ring of logit rows)

__global__ __launch_bounds__(64) void crf_nll_kernel(
    const float* __restrict__ logits,   // [N, T, C] f32
    const int*   __restrict__ lengths,  // [N] i32
    const int*   __restrict__ tags,     // [N, T] i32
    const float* __restrict__ trans,    // [C, C] f32
    float* __restrict__ out, int N)
{
    const int n    = blockIdx.x;
    if (n >= N) return;
    const int lane = threadIdx.x;   // class index i, 0..63

    __shared__ __align__(16) float f_lds[NCLS];

    // ---- transition row `lane`: max, row-sum, exp-space (expT/64) ----
    float trow[NCLS];
    #pragma unroll
    for (int j = 0; j < NCLS; j += 4) {
        const float4 v = *reinterpret_cast<const float4*>(&trans[lane * NCLS + j]);
        trow[j]   = v.x; trow[j+1] = v.y; trow[j+2] = v.z; trow[j+3] = v.w;
    }
    float tmax = -3.0e38f, tsum = 0.f;
    #pragma unroll
    for (int j = 0; j < NCLS; ++j) { tmax = fmaxf(tmax, trow[j]); tsum += trow[j]; }
    float mT = tmax;
    #pragma unroll
    for (int o = 32; o; o >>= 1) mT = fmaxf(mT, __shfl_xor(mT, o));
    #pragma unroll
    for (int j = 0; j < NCLS; ++j) trow[j] = __expf(trow[j] - mT) * 0.015625f;

    const int len = lengths[n];               // in [1, T-1]
    const float* lg = logits + (size_t)n * TDIM * NCLS;
    const float INV_C = 1.0f / (float)NCLS;

    // ---- exp-space recurrence ----
    // alpha_i(t) = B_t + ln f_i, B_t = t*(mT+ln64) + B_renorm (uniform, analytic)
    // f'_i = (sum_j expT[i,j] * f_j) * p_i,  p_i = exp(logit_t,i / 64)
    float f = 1.0f;
    float B = 0.0f;

    // 8-deep register ring of logit rows: lgr[k] holds row 8b+k at block b.
    float lgr[PD];
    #pragma unroll
    for (int k = 0; k < PD; ++k) lgr[k] = lg[(size_t)k * NCLS + lane]; // rows 0..7 always exist (T=512)

    const int nblk = len >> 3;
    const int tail = len & 7;

    // one recurrence step; f_lds round-trip + 64 FMAs is the critical chain
    #define CRF_STEP(PVAL)                                                     \
    {                                                                          \
        f_lds[lane] = f;                                                       \
        asm volatile("s_waitcnt lgkmcnt(0)" ::: "memory");                     \
        float d0 = 0.f, d1 = 0.f, d2 = 0.f, d3 = 0.f;                          \
        float d4 = 0.f, d5 = 0.f, d6 = 0.f, d7 = 0.f;                          \
        _Pragma("unroll")                                                      \
        for (int j = 0; j < NCLS; j += 8) {                                    \
            const float4 a = *reinterpret_cast<const float4*>(&f_lds[j]);      \
            const float4 b4 = *reinterpret_cast<const float4*>(&f_lds[j + 4]); \
            d0 = fmaf(trow[j + 0], a.x,  d0);                                  \
            d1 = fmaf(trow[j + 1], a.y,  d1);                                  \
            d2 = fmaf(trow[j + 2], a.z,  d2);                                  \
            d3 = fmaf(trow[j + 3], a.w,  d3);                                  \
            d4 = fmaf(trow[j + 4], b4.x, d4);                                  \
            d5 = fmaf(trow[j + 5], b4.y, d5);                                  \
            d6 = fmaf(trow[j + 6], b4.z, d6);                                  \
            d7 = fmaf(trow[j + 7], b4.w, d7);                                  \
        }                                                                      \
        const float dot = ((d0 + d1) + (d2 + d3)) + ((d4 + d5) + (d6 + d7));   \
        f = dot * (PVAL);                                                      \
    }

    int t = 0;
    for (int b = 0; b < nblk; ++b) {
        #pragma unroll
        for (int k = 0; k < PD; ++k) {
            // p for step t+k from a row loaded 8 steps ago (off critical path)
            const float p = __expf(lgr[k] * INV_C);
            // issue replacement load (row t+k+8) -> lands 8 steps from now
            int nidx = t + k + PD; nidx = (nidx > TDIM - 1) ? (TDIM - 1) : nidx;
            lgr[k] = lg[(size_t)nidx * NCLS + lane];
            CRF_STEP(p);
        }
        t += PD;
        // periodic renorm: keep f in fp32 range (every 64 steps)
        if ((b & 7) == 7) {
            float r = __shfl(f, 0);
            r = fmaxf(r, 1e-30f);
            f *= __builtin_amdgcn_rcpf(r);
            B += __logf(r);
        }
    }

    // tail: 0..7 steps, static ring indices, uniform branches
    #pragma unroll
    for (int k = 0; k < PD - 1; ++k) {
        if (k < tail) {
            const float p = __expf(lgr[k] * INV_C);
            CRF_STEP(p);
        }
    }
    #undef CRF_STEP

    // ---- gold score (parallel, off the serial chain) ----
    const int* tg = tags + (size_t)n * TDIM;
    float g = 0.f;
    for (int m = 1 + lane; m <= len; m += 64) {
        const int tm = tg[m];
        const int tp = tg[m - 1];
        g += trans[tm * NCLS + tp] + lg[(size_t)m * NCLS + tm];
    }

    // ---- combine: out = 64*B_len + sum_i(ln f_i - g_i) - first ----
    float v = __logf(f) - g;
    #pragma unroll
    for (int o = 32; o; o >>= 1) v += __shfl_xor(v, o);

    const int   t0 = tg[0];
    const float rs = __shfl(tsum, t0);   // row-sum of T at row tags[0]

    if (lane == 0) {
        const float Bt    = (float)len * (mT + 4.1588830833596715f) + B; // ln(64)
        const float first = lg[t0] + rs;
        out[n] = 64.0f * Bt + v - first;
    }
}

extern "C" void kernel_launch(void* const* d_in, const int* in_sizes, int n_in,
                              void* d_out, int out_size, void* d_ws, size_t ws_size,
                              hipStream_t stream) {
    const float* logits  = (const float*)d_in[0];
    const int*   lengths = (const int*)  d_in[1];
    const int*   tags    = (const int*)  d_in[2];
    const float* trans   = (const float*)d_in[3];
    float* out = (float*)d_out;
    const int N = in_sizes[1];   // 512

    crf_nll_kernel<<<N, 64, 0, stream>>>(logits, lengths, tags, trans, out, N);
}

// Round 4
// 90.912 us; speedup vs baseline: 4.2398x; 1.9315x over previous
//
#include <hip/hip_runtime.h>

#define NCLS 64
#define TDIM 512
#define PD   8   // prefetch depth (ring of logit rows)

typedef _Float16 h2 __attribute__((ext_vector_type(2)));

#if __has_builtin(__builtin_amdgcn_fdot2)
#define FDOT2(a, b, c) __builtin_amdgcn_fdot2((a), (b), (c), false)
#else
static __device__ __forceinline__ float FDOT2(h2 a, h2 b, float c) {
    return fmaf((float)a.x, (float)b.x, fmaf((float)a.y, (float)b.y, c));
}
#endif

#define BC_H2(x) __builtin_bit_cast(h2, (x))

__global__ __launch_bounds__(64) void crf_nll_kernel(
    const float* __restrict__ logits,   // [N, T, C] f32
    const int*   __restrict__ lengths,  // [N] i32
    const int*   __restrict__ tags,     // [N, T] i32
    const float* __restrict__ trans,    // [C, C] f32
    float* __restrict__ out, int N)
{
    const int n    = blockIdx.x;
    if (n >= N) return;
    const int lane = threadIdx.x;   // class index i, 0..63

    __shared__ __align__(16) _Float16 fh_lds[NCLS];

    const int len = lengths[n];               // in [1, T-1]
    const float* lg = logits + (size_t)n * TDIM * NCLS;
    const int*   tg = tags   + (size_t)n * TDIM;
    const float INV_C = 1.0f / (float)NCLS;

    // ---- preload all tags for this sample (used in gold-score tail) ----
    int tr8[PD];
    #pragma unroll
    for (int k = 0; k < PD; ++k) tr8[k] = tg[lane + NCLS * k];

    // ---- transition row `lane`: max, row-sum, exp-space, pack to f16 ----
    float trow[NCLS];
    #pragma unroll
    for (int j = 0; j < NCLS; j += 4) {
        const float4 v = *reinterpret_cast<const float4*>(&trans[lane * NCLS + j]);
        trow[j]   = v.x; trow[j+1] = v.y; trow[j+2] = v.z; trow[j+3] = v.w;
    }
    float tmax = -3.0e38f, tsum = 0.f;
    #pragma unroll
    for (int j = 0; j < NCLS; ++j) { tmax = fmaxf(tmax, trow[j]); tsum += trow[j]; }
    float mT = tmax;
    #pragma unroll
    for (int o = 32; o; o >>= 1) mT = fmaxf(mT, __shfl_xor(mT, o));
    // expT[i][j] = exp(T[i][j] - mT) / 64, packed as 32 half2
    h2 tp[NCLS / 2];
    #pragma unroll
    for (int j = 0; j < NCLS; j += 2) {
        const float e0 = __expf(trow[j]     - mT) * 0.015625f;
        const float e1 = __expf(trow[j + 1] - mT) * 0.015625f;
        h2 p; p.x = (_Float16)e0; p.y = (_Float16)e1;
        tp[j >> 1] = p;
    }

    // first-step bits computed early so their gathers issue now
    const int   t0 = __shfl(tr8[0], 0);          // tags[0]
    const float rs = __shfl(tsum, t0);           // row-sum of T at row tags[0]
    const float first = lg[t0] + rs;

    // ---- exp-space recurrence ----
    // alpha_i(t) = B_t + ln f_i, B_t = t*(mT+ln64) + B_renorm (uniform, analytic)
    // f'_i = (sum_j expT[i,j] * f_j) * p_i,  p_i = exp(logit_t,i / 64)
    float f = 1.0f;
    float B = 0.0f;

    float lgr[PD];
    #pragma unroll
    for (int k = 0; k < PD; ++k) lgr[k] = lg[(size_t)k * NCLS + lane];

    const int nblk = len >> 3;
    const int tail = len & 7;

    // one recurrence step. Same-wave DS ops complete in-order, so no explicit
    // lgkmcnt drain between the b16 write and the b128 reads; compiler inserts
    // counted lgkm waits before each use.
    #define CRF_STEP(PVAL)                                                     \
    {                                                                          \
        fh_lds[lane] = (_Float16)f;                                            \
        float d0 = 0.f, d1 = 0.f, d2 = 0.f, d3 = 0.f;                          \
        _Pragma("unroll")                                                      \
        for (int j = 0; j < NCLS; j += 16) {                                   \
            const float4 a  = *reinterpret_cast<const float4*>(&fh_lds[j]);    \
            const float4 b4 = *reinterpret_cast<const float4*>(&fh_lds[j+8]);  \
            d0 = FDOT2(tp[(j >> 1) + 0], BC_H2(a.x),  d0);                     \
            d1 = FDOT2(tp[(j >> 1) + 1], BC_H2(a.y),  d1);                     \
            d2 = FDOT2(tp[(j >> 1) + 2], BC_H2(a.z),  d2);                     \
            d3 = FDOT2(tp[(j >> 1) + 3], BC_H2(a.w),  d3);                     \
            d0 = FDOT2(tp[(j >> 1) + 4], BC_H2(b4.x), d0);                     \
            d1 = FDOT2(tp[(j >> 1) + 5], BC_H2(b4.y), d1);                     \
            d2 = FDOT2(tp[(j >> 1) + 6], BC_H2(b4.z), d2);                     \
            d3 = FDOT2(tp[(j >> 1) + 7], BC_H2(b4.w), d3);                     \
        }                                                                      \
        const float dot = (d0 + d1) + (d2 + d3);                               \
        f = dot * (PVAL);                                                      \
    }

    int t = 0;
    for (int b = 0; b < nblk; ++b) {
        #pragma unroll
        for (int k = 0; k < PD; ++k) {
            const float p = __expf(lgr[k] * INV_C);      // off critical path
            int nidx = t + k + PD; nidx = (nidx > TDIM - 1) ? (TDIM - 1) : nidx;
            lgr[k] = lg[(size_t)nidx * NCLS + lane];     // lands 8 steps out
            CRF_STEP(p);
        }
        t += PD;
        if ((b & 7) == 7) {            // periodic renorm: keep f in f32/f16 range
            float r = __shfl(f, 0);
            r = fmaxf(r, 1e-30f);
            f *= __builtin_amdgcn_rcpf(r);
            B += __logf(r);
        }
    }

    #pragma unroll
    for (int k = 0; k < PD - 1; ++k) {
        if (k < tail) {
            const float p = __expf(lgr[k] * INV_C);
            CRF_STEP(p);
        }
    }
    #undef CRF_STEP

    // ---- gold score: tags already in registers; all gathers issue at once ----
    float g = 0.f;
    #pragma unroll
    for (int k = 0; k < PD; ++k) {
        const int m = 1 + lane + NCLS * k;
        if (m <= len) {
            const int rot  = __shfl(tr8[k], (lane + 1) & 63);        // tg[m], lane<63
            const int wrap = __shfl(tr8[(k + 1) & (PD - 1)], 0);     // tg[m], lane==63
            const int tm = (lane == 63) ? wrap : rot;
            const int tp_ = tr8[k];                                   // tg[m-1]
            g += trans[tm * NCLS + tp_] + lg[(size_t)m * NCLS + tm];
        }
    }

    // ---- combine: out = 64*B_len + sum_i(ln f_i - g_i) - first ----
    float v = __logf(f) - g;
    #pragma unroll
    for (int o = 32; o; o >>= 1) v += __shfl_xor(v, o);

    if (lane == 0) {
        const float Bt = (float)len * (mT + 4.1588830833596715f) + B; // ln(64)
        out[n] = 64.0f * Bt + v - first;
    }
}

extern "C" void kernel_launch(void* const* d_in, const int* in_sizes, int n_in,
                              void* d_out, int out_size, void* d_ws, size_t ws_size,
                              hipStream_t stream) {
    const float* logits  = (const float*)d_in[0];
    const int*   lengths = (const int*)  d_in[1];
    const int*   tags    = (const int*)  d_in[2];
    const float* trans   = (const float*)d_in[3];
    float* out = (float*)d_out;
    const int N = in_sizes[1];   // 512

    crf_nll_kernel<<<N, 64, 0, stream>>>(logits, lengths, tags, trans, out, N);
}